// Round 1
// baseline (386.549 us; speedup 1.0000x reference)
//
#include <hip/hip_runtime.h>

#define D 64

// ws layout (floats): [0,4096) = U^T, [4096,8192) = V^T, [8192,8256) = c = W@s + bias
__global__ void dmc_prep(const float* __restrict__ s,
                         const float* __restrict__ U,
                         const float* __restrict__ V,
                         const float* __restrict__ W,
                         const float* __restrict__ bias,
                         float* __restrict__ ws) {
  const int t = threadIdx.x;
  float* Ut = ws;
  float* Vt = ws + D * D;
  float* c  = ws + 2 * D * D;
  for (int idx = t; idx < D * D; idx += blockDim.x) {
    const int r = idx >> 6;
    const int col = idx & (D - 1);
    Ut[col * D + r] = U[idx];
    Vt[col * D + r] = V[idx];
  }
  if (t < D) {
    float acc = bias[t];
    #pragma unroll
    for (int k = 0; k < D; ++k) acc = fmaf(W[t * D + k], s[k], acc);
    c[t] = acc;
  }
}

// One thread owns one 64-dim block-row. U^T/V^T/c/s are wave-uniform ->
// compiler emits scalar (s_load) reads; the fmac stream is pure VALU at
// 64 rows per wave instruction.
__global__ __launch_bounds__(256, 2) void dmc_main(
    const float* __restrict__ h,
    const float* __restrict__ keys,
    const float* __restrict__ s,
    const float* __restrict__ prelu_a,
    const float* __restrict__ ws,
    float* __restrict__ out,
    const int nblocks) {
  const float* __restrict__ Ut = ws;
  const float* __restrict__ Vt = ws + D * D;
  const float* __restrict__ c  = ws + 2 * D * D;
  const float a = prelu_a[0];

  const int j = blockIdx.x * blockDim.x + threadIdx.x;
  if (j >= nblocks) return;

  const float* __restrict__ hr = h + (size_t)j * D;
  const float* __restrict__ kr = keys + (size_t)j * D;

  float hb[D], kb[D];
  #pragma unroll
  for (int q = 0; q < D / 4; ++q) {
    const float4 v = reinterpret_cast<const float4*>(hr)[q];
    hb[4 * q + 0] = v.x; hb[4 * q + 1] = v.y;
    hb[4 * q + 2] = v.z; hb[4 * q + 3] = v.w;
    const float4 w = reinterpret_cast<const float4*>(kr)[q];
    kb[4 * q + 0] = w.x; kb[4 * q + 1] = w.y;
    kb[4 * q + 2] = w.z; kb[4 * q + 3] = w.w;
  }

  float pre[D];
  #pragma unroll
  for (int i = 0; i < D; ++i) pre[i] = c[i];

  float gdot = 0.0f;
  #pragma unroll
  for (int k = 0; k < D; ++k) {
    gdot = fmaf(hb[k] + kb[k], s[k], gdot);
    const float hv = hb[k];
    const float kv = kb[k];
    const float* __restrict__ utr = Ut + k * D;
    const float* __restrict__ vtr = Vt + k * D;
    #pragma unroll
    for (int i = 0; i < D; ++i) {
      pre[i] = fmaf(hv, utr[i], fmaf(kv, vtr[i], pre[i]));
    }
  }

  const float g = 1.0f / (1.0f + __expf(-gdot));
  float ss = 0.0f;
  #pragma unroll
  for (int i = 0; i < D; ++i) {
    const float p = pre[i];
    const float act = (p >= 0.0f) ? p : a * p;
    const float hn = fmaf(g, act, hb[i]);
    pre[i] = hn;
    ss = fmaf(hn, hn, ss);
  }
  const float rn = rsqrtf(ss);

  float* __restrict__ orow = out + (size_t)j * D;
  #pragma unroll
  for (int q = 0; q < D / 4; ++q) {
    float4 v;
    v.x = pre[4 * q + 0] * rn;
    v.y = pre[4 * q + 1] * rn;
    v.z = pre[4 * q + 2] * rn;
    v.w = pre[4 * q + 3] * rn;
    reinterpret_cast<float4*>(orow)[q] = v;
  }
}

extern "C" void kernel_launch(void* const* d_in, const int* in_sizes, int n_in,
                              void* d_out, int out_size, void* d_ws, size_t ws_size,
                              hipStream_t stream) {
  const float* s       = (const float*)d_in[0];
  const float* h       = (const float*)d_in[1];
  const float* keys    = (const float*)d_in[2];
  const float* U       = (const float*)d_in[3];
  const float* V       = (const float*)d_in[4];
  const float* W       = (const float*)d_in[5];
  const float* bias    = (const float*)d_in[6];
  const float* prelu_a = (const float*)d_in[7];
  float* out = (float*)d_out;
  float* ws  = (float*)d_ws;

  const int nblocks = in_sizes[1] / D;

  dmc_prep<<<1, 256, 0, stream>>>(s, U, V, W, bias, ws);
  const int grid = (nblocks + 255) / 256;
  dmc_main<<<grid, 256, 0, stream>>>(h, keys, s, prelu_a, ws, out, nblocks);
}